// Round 11
// baseline (788.574 us; speedup 1.0000x reference)
//
#include <hip/hip_runtime.h>
#include <hip/hip_bf16.h>
#include <hip/hip_fp16.h>

typedef _Float16 h2vec __attribute__((ext_vector_type(2)));
typedef _Float16 f16x8 __attribute__((ext_vector_type(8)));
typedef float f32x4 __attribute__((ext_vector_type(4)));

static __device__ __forceinline__ float fast_sigmoid(float x) {
  return __builtin_amdgcn_rcpf(1.f + __expf(-x));
}
static __device__ __forceinline__ float fast_tanh(float x) {
  return 1.f - 2.f * __builtin_amdgcn_rcpf(__expf(2.f * x) + 1.f);
}
static __device__ __forceinline__ float fdot2u(unsigned int a, unsigned int b, float c) {
#if __has_builtin(__builtin_amdgcn_fdot2)
  return __builtin_amdgcn_fdot2(__builtin_bit_cast(h2vec, a),
                                __builtin_bit_cast(h2vec, b), c, false);
#else
  h2vec av = __builtin_bit_cast(h2vec, a);
  h2vec bv = __builtin_bit_cast(h2vec, b);
  return c + (float)av[0] * (float)bv[0] + (float)av[1] * (float)bv[1];
#endif
}
template<int CTRL>
static __device__ __forceinline__ float dpp_add(float v) {
  int x = __builtin_bit_cast(int, v);
  int y = __builtin_amdgcn_update_dpp(0, x, CTRL, 0xF, 0xF, true);
  return v + __builtin_bit_cast(float, y);
}
template<int CTRL>
static __device__ __forceinline__ float dpp_mov(float v) {
  int x = __builtin_bit_cast(int, v);
  int y = __builtin_amdgcn_update_dpp(0, x, CTRL, 0xF, 0xF, true);
  return __builtin_bit_cast(float, y);
}

// ---------------------------------------------------------------------------
// A-tile staging helper: f32 or f16 source -> f16 swizzled LDS rows (128B).
// ---------------------------------------------------------------------------
template<typename AT>
static __device__ __forceinline__ void stage_row32(
    const AT* __restrict__ src, unsigned char* __restrict__ dst,
    int row, int kc) {
#pragma unroll
  for (int u = 0; u < 4; ++u) {
    f16x8 h;
    if constexpr (sizeof(AT) == 4) {
      float4 v0 = *reinterpret_cast<const float4*>((const float*)src + u * 8);
      float4 v1 = *reinterpret_cast<const float4*>((const float*)src + u * 8 + 4);
      h[0] = (_Float16)v0.x; h[1] = (_Float16)v0.y;
      h[2] = (_Float16)v0.z; h[3] = (_Float16)v0.w;
      h[4] = (_Float16)v1.x; h[5] = (_Float16)v1.y;
      h[6] = (_Float16)v1.z; h[7] = (_Float16)v1.w;
    } else {
      h = *reinterpret_cast<const f16x8*>((const __half*)src + u * 8);
    }
    const int kbyte = (kc + u * 8) * 2;
    *reinterpret_cast<f16x8*>(&dst[row * 128 + (kbyte ^ ((row & 7) << 4))]) = h;
  }
}

// ---------------------------------------------------------------------------
// f16-MFMA GEMM. C = act(A @ W^T + bias). Proven 128x64x64 swizzled tile.
// MODE 0: +b0+b1; MODE 1: relu(+b0); MODE 2: tanh(+b0).
// ---------------------------------------------------------------------------
template<typename AT, typename OT, int MODE>
__global__ __launch_bounds__(256) void gemm_mfma2(
    const AT* __restrict__ A, const float* __restrict__ W,
    const float* __restrict__ b0, const float* __restrict__ b1,
    OT* __restrict__ C, int M, int N, int K) {
  __shared__ __align__(16) unsigned char As[128 * 128];
  __shared__ __align__(16) unsigned char Bs[64 * 128];
  const int tid = threadIdx.x;
  const int wave = tid >> 6, l = tid & 63;
  const int wm = wave >> 1, wn = wave & 1;
  const int m0 = blockIdx.x * 128, n0 = blockIdx.y * 64;
  const int lrow = l & 15, lq = l >> 4;

  f32x4 acc[4][2] = {};
  const int arow = tid >> 1, akc = (tid & 1) * 32;
  const int brow = tid >> 2, bkc = (tid & 3) * 16;

  for (int k0 = 0; k0 < K; k0 += 64) {
    stage_row32<AT>(A + (size_t)(m0 + arow) * K + k0 + akc, As, arow, akc);
    {
      const float* src = W + (size_t)(n0 + brow) * K + k0 + bkc;
#pragma unroll
      for (int u = 0; u < 2; ++u) {
        float4 v0 = *reinterpret_cast<const float4*>(src + u * 8);
        float4 v1 = *reinterpret_cast<const float4*>(src + u * 8 + 4);
        f16x8 h;
        h[0] = (_Float16)v0.x; h[1] = (_Float16)v0.y;
        h[2] = (_Float16)v0.z; h[3] = (_Float16)v0.w;
        h[4] = (_Float16)v1.x; h[5] = (_Float16)v1.y;
        h[6] = (_Float16)v1.z; h[7] = (_Float16)v1.w;
        const int kbyte = (bkc + u * 8) * 2;
        *reinterpret_cast<f16x8*>(&Bs[brow * 128 + (kbyte ^ ((brow & 7) << 4))]) = h;
      }
    }
    __syncthreads();
#pragma unroll
    for (int kk = 0; kk < 64; kk += 32) {
      const int kbyte = (kk + lq * 8) * 2;
      f16x8 af[4], bf[2];
#pragma unroll
      for (int mt = 0; mt < 4; ++mt) {
        const int row = wm * 64 + mt * 16 + lrow;
        af[mt] = *reinterpret_cast<const f16x8*>(&As[row * 128 + (kbyte ^ ((row & 7) << 4))]);
      }
#pragma unroll
      for (int nt = 0; nt < 2; ++nt) {
        const int row = wn * 32 + nt * 16 + lrow;
        bf[nt] = *reinterpret_cast<const f16x8*>(&Bs[row * 128 + (kbyte ^ ((row & 7) << 4))]);
      }
#pragma unroll
      for (int mt = 0; mt < 4; ++mt)
#pragma unroll
        for (int nt = 0; nt < 2; ++nt)
          acc[mt][nt] = __builtin_amdgcn_mfma_f32_16x16x32_f16(af[mt], bf[nt], acc[mt][nt], 0, 0, 0);
    }
    __syncthreads();
  }

#pragma unroll
  for (int nt = 0; nt < 2; ++nt) {
    const int n = n0 + wn * 32 + nt * 16 + lrow;
    float bias = (MODE == 0) ? (b0[n] + b1[n]) : b0[n];
#pragma unroll
    for (int mt = 0; mt < 4; ++mt) {
#pragma unroll
      for (int r = 0; r < 4; ++r) {
        const int m = m0 + wm * 64 + mt * 16 + lq * 4 + r;
        float val = acc[mt][nt][r] + bias;
        if (MODE == 1) val = fmaxf(val, 0.f);
        if (MODE == 2) val = fast_tanh(val);
        if constexpr (sizeof(OT) == 2)
          C[(size_t)m * N + n] = __float2half_rn(val);
        else
          C[(size_t)m * N + n] = val;
      }
    }
  }
}

// ---------------------------------------------------------------------------
// Fused fw+bw input-projection GEMM, f16 output. blockIdx.z = direction.
// ---------------------------------------------------------------------------
template<typename AT>
__global__ __launch_bounds__(256) void gemm_proj_h(
    const AT* __restrict__ A,
    const float* __restrict__ W0, const float* __restrict__ W1,
    const float* __restrict__ bi0, const float* __restrict__ bh0,
    const float* __restrict__ bi1, const float* __restrict__ bh1,
    __half* __restrict__ C0, __half* __restrict__ C1, int M, int N, int K) {
  const float* __restrict__ W  = blockIdx.z ? W1 : W0;
  const float* __restrict__ b0 = blockIdx.z ? bi1 : bi0;
  const float* __restrict__ b1 = blockIdx.z ? bh1 : bh0;
  __half* __restrict__ C = blockIdx.z ? C1 : C0;

  __shared__ __align__(16) unsigned char As[128 * 128];
  __shared__ __align__(16) unsigned char Bs[64 * 128];
  const int tid = threadIdx.x;
  const int wave = tid >> 6, l = tid & 63;
  const int wm = wave >> 1, wn = wave & 1;
  const int m0 = blockIdx.x * 128, n0 = blockIdx.y * 64;
  const int lrow = l & 15, lq = l >> 4;

  f32x4 acc[4][2] = {};
  const int arow = tid >> 1, akc = (tid & 1) * 32;
  const int brow = tid >> 2, bkc = (tid & 3) * 16;

  for (int k0 = 0; k0 < K; k0 += 64) {
    stage_row32<AT>(A + (size_t)(m0 + arow) * K + k0 + akc, As, arow, akc);
    {
      const float* src = W + (size_t)(n0 + brow) * K + k0 + bkc;
#pragma unroll
      for (int u = 0; u < 2; ++u) {
        float4 v0 = *reinterpret_cast<const float4*>(src + u * 8);
        float4 v1 = *reinterpret_cast<const float4*>(src + u * 8 + 4);
        f16x8 h;
        h[0] = (_Float16)v0.x; h[1] = (_Float16)v0.y;
        h[2] = (_Float16)v0.z; h[3] = (_Float16)v0.w;
        h[4] = (_Float16)v1.x; h[5] = (_Float16)v1.y;
        h[6] = (_Float16)v1.z; h[7] = (_Float16)v1.w;
        const int kbyte = (bkc + u * 8) * 2;
        *reinterpret_cast<f16x8*>(&Bs[brow * 128 + (kbyte ^ ((brow & 7) << 4))]) = h;
      }
    }
    __syncthreads();
#pragma unroll
    for (int kk = 0; kk < 64; kk += 32) {
      const int kbyte = (kk + lq * 8) * 2;
      f16x8 af[4], bf[2];
#pragma unroll
      for (int mt = 0; mt < 4; ++mt) {
        const int row = wm * 64 + mt * 16 + lrow;
        af[mt] = *reinterpret_cast<const f16x8*>(&As[row * 128 + (kbyte ^ ((row & 7) << 4))]);
      }
#pragma unroll
      for (int nt = 0; nt < 2; ++nt) {
        const int row = wn * 32 + nt * 16 + lrow;
        bf[nt] = *reinterpret_cast<const f16x8*>(&Bs[row * 128 + (kbyte ^ ((row & 7) << 4))]);
      }
#pragma unroll
      for (int mt = 0; mt < 4; ++mt)
#pragma unroll
        for (int nt = 0; nt < 2; ++nt)
          acc[mt][nt] = __builtin_amdgcn_mfma_f32_16x16x32_f16(af[mt], bf[nt], acc[mt][nt], 0, 0, 0);
    }
    __syncthreads();
  }

#pragma unroll
  for (int nt = 0; nt < 2; ++nt) {
    const int n = n0 + wn * 32 + nt * 16 + lrow;
    const float bias = b0[n] + b1[n];
#pragma unroll
    for (int mt = 0; mt < 4; ++mt) {
#pragma unroll
      for (int r = 0; r < 4; ++r) {
        const int m = m0 + wm * 64 + mt * 16 + lq * 4 + r;
        C[(size_t)m * N + n] = __float2half_rn(acc[mt][nt][r] + bias);
      }
    }
  }
}

// ---------------------------------------------------------------------------
// LSTM recurrence, v8: 256 threads (4 waves = 1 wave/SIMD -> no cross-wave
// issue interference, 4-wave barrier group) per (batch, direction).
// Lane (j2 = tid>>2 unit-pair, kq = tid&3 k-quarter): 8 gate-rows
// (2 units x 4 gates) over k-quarter = 128 dot2/lane. Quad DPP butterfly
// gives all 8 sums to all quad lanes; lane kq activates gate kq for both
// units (tanh via 2*sigmoid(2x)-1), quad_perm broadcasts redistribute.
// h as f16x2 in LDS[2][64] (2-way bank alias = free), double-buffered.
// Raw s_barrier with lgkmcnt(0)-only wait; f16 xg, prefetch depth 2.
// ---------------------------------------------------------------------------
__global__ __launch_bounds__(256, 1) void lstm_seq8(
    const __half* __restrict__ xg_f, const __half* __restrict__ xg_b,
    const float* __restrict__ Whh_f, const float* __restrict__ Whh_b,
    __half* __restrict__ out) {
  const int b = blockIdx.x;
  const int dir = blockIdx.y;
  const int tid = threadIdx.x;
  const int j2 = tid >> 2;  // unit pair 0..63
  const int kq = tid & 3;   // k quarter
  const __half* __restrict__ xg = dir ? xg_b : xg_f;
  const float* __restrict__ Whh = dir ? Whh_b : Whh_f;

  __shared__ unsigned int hbuf[2][64];  // f16x2 per unit pair, double-buffered

  // Weights: w[g][u][kk] = f16x2 of row (g*128 + 2*j2 + u), k = kq*32 + 2*kk
  unsigned int w[4][2][16];
#pragma unroll
  for (int g = 0; g < 4; ++g)
#pragma unroll
    for (int u = 0; u < 2; ++u) {
      const float4* wr = reinterpret_cast<const float4*>(
          Whh + (size_t)(g * 128 + 2 * j2 + u) * 128 + kq * 32);
#pragma unroll
      for (int q = 0; q < 8; ++q) {
        float4 v = wr[q];
        __half2 p0 = __floats2half2_rn(v.x, v.y);
        __half2 p1 = __floats2half2_rn(v.z, v.w);
        w[g][u][2 * q]     = __builtin_bit_cast(unsigned int, p0);
        w[g][u][2 * q + 1] = __builtin_bit_cast(unsigned int, p1);
      }
    }

  if (tid < 128) hbuf[tid >> 6][tid & 63] = 0u;
  float c0 = 0.f, c1 = 0.f;
  __syncthreads();

  const int tt0 = dir ? 511 : 0;
  const int stp = dir ? -1 : 1;
  const size_t base = (size_t)b * 512 * 512;
  const int xoff = kq * 128 + 2 * j2;  // f16 index of (gate kq, unit 2*j2)

  unsigned int xva = *reinterpret_cast<const unsigned int*>(xg + base + (size_t)tt0 * 512 + xoff);
  unsigned int xvb = *reinterpret_cast<const unsigned int*>(xg + base + (size_t)(tt0 + stp) * 512 + xoff);

  auto step = [&](int t, unsigned int* rbuf, unsigned int* wbuf, unsigned int& xcur)
      __attribute__((always_inline)) {
    const int tt = tt0 + stp * t;

    // my h quarter: 4 x ds_read_b128 (2-way bank alias across kq = free)
    const uint4* hc = reinterpret_cast<const uint4*>(&rbuf[kq * 16]);
    uint4 q0 = hc[0], q1 = hc[1], q2 = hc[2], q3 = hc[3];
    unsigned int ha[16];
    ha[0] = q0.x; ha[1] = q0.y; ha[2] = q0.z; ha[3] = q0.w;
    ha[4] = q1.x; ha[5] = q1.y; ha[6] = q1.z; ha[7] = q1.w;
    ha[8] = q2.x; ha[9] = q2.y; ha[10] = q2.z; ha[11] = q2.w;
    ha[12] = q3.x; ha[13] = q3.y; ha[14] = q3.z; ha[15] = q3.w;

    float acc[4][2] = {};
#pragma unroll
    for (int kk = 0; kk < 16; ++kk) {
#pragma unroll
      for (int g = 0; g < 4; ++g) {
        acc[g][0] = fdot2u(w[g][0][kk], ha[kk], acc[g][0]);
        acc[g][1] = fdot2u(w[g][1][kk], ha[kk], acc[g][1]);
      }
    }

    // quad butterfly: all 4 lanes get all 8 full sums
#pragma unroll
    for (int g = 0; g < 4; ++g)
#pragma unroll
      for (int u = 0; u < 2; ++u) {
        float a = acc[g][u];
        a = dpp_add<0xB1>(a);  // xor 1
        a = dpp_add<0x4E>(a);  // xor 2
        acc[g][u] = a;
      }

    // xg for this lane's gate (kq) of units 2*j2, 2*j2+1
    const __half2 xh = __builtin_bit_cast(__half2, xcur);
    // prefetch xg for t+2 (in flight across raw barriers)
    {
      const int t2 = t + 2;
      const int tt2 = (t2 < 512) ? (tt0 + stp * t2) : tt0;
      xcur = *reinterpret_cast<const unsigned int*>(xg + base + (size_t)tt2 * 512 + xoff);
    }

    float h01[2];
#pragma unroll
    for (int u = 0; u < 2; ++u) {
      float a = acc[0][u];
      a = (kq == 1) ? acc[1][u] : a;
      a = (kq == 2) ? acc[2][u] : a;
      a = (kq == 3) ? acc[3][u] : a;
      a += (u == 0) ? __low2float(xh) : __high2float(xh);

      const float xs = (kq == 2) ? 2.f * a : a;
      const float y = fast_sigmoid(xs);
      const float act = (kq == 2) ? 2.f * y - 1.f : y;

      const float gi = dpp_mov<0x00>(act);
      const float gf = dpp_mov<0x55>(act);
      const float gg = dpp_mov<0xAA>(act);
      const float go = dpp_mov<0xFF>(act);

      float& c = (u == 0) ? c0 : c1;
      c = gf * c + gi * gg;
      h01[u] = go * (2.f * fast_sigmoid(2.f * c) - 1.f);
    }

    const __half2 hp = __floats2half2_rn(h01[0], h01[1]);
    if (kq == 0) {  // h pair -> next step's buffer
      wbuf[j2] = __builtin_bit_cast(unsigned int, hp);
    }
    if (kq == 1) {  // h pair -> global out (f16)
      *reinterpret_cast<__half2*>(
          out + ((size_t)b * 512 + tt) * 256 + dir * 128 + 2 * j2) = hp;
    }

    asm volatile("s_waitcnt lgkmcnt(0)" ::: "memory");
    __builtin_amdgcn_s_barrier();
    asm volatile("" ::: "memory");
  };

  for (int it = 0; it < 256; ++it) {
    step(2 * it,     hbuf[0], hbuf[1], xva);
    step(2 * it + 1, hbuf[1], hbuf[0], xvb);
  }
}

// ---------------------------------------------------------------------------
// Launcher
// ---------------------------------------------------------------------------
extern "C" void kernel_launch(void* const* d_in, const int* in_sizes, int n_in,
                              void* d_out, int out_size, void* d_ws, size_t ws_size,
                              hipStream_t stream) {
  (void)in_sizes; (void)n_in; (void)out_size; (void)ws_size;

  const float* x     = (const float*)d_in[0];
  const float* Wih00 = (const float*)d_in[1];
  const float* Whh00 = (const float*)d_in[2];
  const float* bih00 = (const float*)d_in[3];
  const float* bhh00 = (const float*)d_in[4];
  const float* Wih01 = (const float*)d_in[5];
  const float* Whh01 = (const float*)d_in[6];
  const float* bih01 = (const float*)d_in[7];
  const float* bhh01 = (const float*)d_in[8];
  const float* Wih10 = (const float*)d_in[9];
  const float* Whh10 = (const float*)d_in[10];
  const float* bih10 = (const float*)d_in[11];
  const float* bhh10 = (const float*)d_in[12];
  const float* Wih11 = (const float*)d_in[13];
  const float* Whh11 = (const float*)d_in[14];
  const float* bih11 = (const float*)d_in[15];
  const float* bhh11 = (const float*)d_in[16];
  const float* W1 = (const float*)d_in[17];
  const float* b1 = (const float*)d_in[18];
  const float* W2 = (const float*)d_in[19];
  const float* b2 = (const float*)d_in[20];
  float* out = (float*)d_out;

  char* ws = (char*)d_ws;
  __half* xgh_f = (__half*)ws;                          // 32 MB [B,T,512] f16
  __half* xgh_b = (__half*)(ws + ((size_t)32 << 20));   // 32 MB
  __half* bufh  = (__half*)(ws + ((size_t)64 << 20));   // 16 MB [B,T,256] f16
  __half* tmph  = (__half*)(ws + ((size_t)80 << 20));   // 16 MB head intermediate

  const int M = 64 * 512;  // 32768 rows

  // ---- layer 0 ----
  gemm_proj_h<float><<<dim3(M / 128, 8, 2), 256, 0, stream>>>(
      x, Wih00, Wih01, bih00, bhh00, bih01, bhh01, xgh_f, xgh_b, M, 512, 64);
  lstm_seq8<<<dim3(64, 2), 256, 0, stream>>>(xgh_f, xgh_b, Whh00, Whh01, bufh);

  // ---- layer 1 ----
  gemm_proj_h<__half><<<dim3(M / 128, 8, 2), 256, 0, stream>>>(
      bufh, Wih10, Wih11, bih10, bhh10, bih11, bhh11, xgh_f, xgh_b, M, 512, 256);
  lstm_seq8<<<dim3(64, 2), 256, 0, stream>>>(xgh_f, xgh_b, Whh10, Whh11, bufh);

  // ---- head ----
  gemm_mfma2<__half, __half, 1><<<dim3(M / 128, 4), 256, 0, stream>>>(
      bufh, W1, b1, nullptr, tmph, M, 256, 256);
  gemm_mfma2<__half, float, 2><<<dim3(M / 128, 1), 256, 0, stream>>>(
      tmph, W2, b2, nullptr, out, M, 64, 256);
}

// Round 12
// 675.147 us; speedup vs baseline: 1.1680x; 1.1680x over previous
//
#include <hip/hip_runtime.h>
#include <hip/hip_bf16.h>
#include <hip/hip_fp16.h>

typedef _Float16 h2vec __attribute__((ext_vector_type(2)));
typedef _Float16 f16x8 __attribute__((ext_vector_type(8)));
typedef float f32x4 __attribute__((ext_vector_type(4)));

static __device__ __forceinline__ float fast_sigmoid(float x) {
  return __builtin_amdgcn_rcpf(1.f + __expf(-x));
}
static __device__ __forceinline__ float fast_tanh(float x) {
  return 1.f - 2.f * __builtin_amdgcn_rcpf(__expf(2.f * x) + 1.f);
}
static __device__ __forceinline__ float fdot2u(unsigned int a, unsigned int b, float c) {
#if __has_builtin(__builtin_amdgcn_fdot2)
  return __builtin_amdgcn_fdot2(__builtin_bit_cast(h2vec, a),
                                __builtin_bit_cast(h2vec, b), c, false);
#else
  h2vec av = __builtin_bit_cast(h2vec, a);
  h2vec bv = __builtin_bit_cast(h2vec, b);
  return c + (float)av[0] * (float)bv[0] + (float)av[1] * (float)bv[1];
#endif
}
template<int CTRL>
static __device__ __forceinline__ float dpp_add(float v) {
  int x = __builtin_bit_cast(int, v);
  int y = __builtin_amdgcn_update_dpp(0, x, CTRL, 0xF, 0xF, true);
  return v + __builtin_bit_cast(float, y);
}
template<int CTRL>
static __device__ __forceinline__ float dpp_mov(float v) {
  int x = __builtin_bit_cast(int, v);
  int y = __builtin_amdgcn_update_dpp(0, x, CTRL, 0xF, 0xF, true);
  return __builtin_bit_cast(float, y);
}

// ---------------------------------------------------------------------------
// A-tile staging helper: f32 or f16 source -> f16 swizzled LDS rows (128B).
// ---------------------------------------------------------------------------
template<typename AT>
static __device__ __forceinline__ void stage_row32(
    const AT* __restrict__ src, unsigned char* __restrict__ dst,
    int row, int kc) {
#pragma unroll
  for (int u = 0; u < 4; ++u) {
    f16x8 h;
    if constexpr (sizeof(AT) == 4) {
      float4 v0 = *reinterpret_cast<const float4*>((const float*)src + u * 8);
      float4 v1 = *reinterpret_cast<const float4*>((const float*)src + u * 8 + 4);
      h[0] = (_Float16)v0.x; h[1] = (_Float16)v0.y;
      h[2] = (_Float16)v0.z; h[3] = (_Float16)v0.w;
      h[4] = (_Float16)v1.x; h[5] = (_Float16)v1.y;
      h[6] = (_Float16)v1.z; h[7] = (_Float16)v1.w;
    } else {
      h = *reinterpret_cast<const f16x8*>((const __half*)src + u * 8);
    }
    const int kbyte = (kc + u * 8) * 2;
    *reinterpret_cast<f16x8*>(&dst[row * 128 + (kbyte ^ ((row & 7) << 4))]) = h;
  }
}

// ---------------------------------------------------------------------------
// f16-MFMA GEMM. C = act(A @ W^T + bias). Proven 128x64x64 swizzled tile.
// MODE 0: +b0+b1; MODE 1: relu(+b0); MODE 2: tanh(+b0).
// ---------------------------------------------------------------------------
template<typename AT, typename OT, int MODE>
__global__ __launch_bounds__(256) void gemm_mfma2(
    const AT* __restrict__ A, const float* __restrict__ W,
    const float* __restrict__ b0, const float* __restrict__ b1,
    OT* __restrict__ C, int M, int N, int K) {
  __shared__ __align__(16) unsigned char As[128 * 128];
  __shared__ __align__(16) unsigned char Bs[64 * 128];
  const int tid = threadIdx.x;
  const int wave = tid >> 6, l = tid & 63;
  const int wm = wave >> 1, wn = wave & 1;
  const int m0 = blockIdx.x * 128, n0 = blockIdx.y * 64;
  const int lrow = l & 15, lq = l >> 4;

  f32x4 acc[4][2] = {};
  const int arow = tid >> 1, akc = (tid & 1) * 32;
  const int brow = tid >> 2, bkc = (tid & 3) * 16;

  for (int k0 = 0; k0 < K; k0 += 64) {
    stage_row32<AT>(A + (size_t)(m0 + arow) * K + k0 + akc, As, arow, akc);
    {
      const float* src = W + (size_t)(n0 + brow) * K + k0 + bkc;
#pragma unroll
      for (int u = 0; u < 2; ++u) {
        float4 v0 = *reinterpret_cast<const float4*>(src + u * 8);
        float4 v1 = *reinterpret_cast<const float4*>(src + u * 8 + 4);
        f16x8 h;
        h[0] = (_Float16)v0.x; h[1] = (_Float16)v0.y;
        h[2] = (_Float16)v0.z; h[3] = (_Float16)v0.w;
        h[4] = (_Float16)v1.x; h[5] = (_Float16)v1.y;
        h[6] = (_Float16)v1.z; h[7] = (_Float16)v1.w;
        const int kbyte = (bkc + u * 8) * 2;
        *reinterpret_cast<f16x8*>(&Bs[brow * 128 + (kbyte ^ ((brow & 7) << 4))]) = h;
      }
    }
    __syncthreads();
#pragma unroll
    for (int kk = 0; kk < 64; kk += 32) {
      const int kbyte = (kk + lq * 8) * 2;
      f16x8 af[4], bf[2];
#pragma unroll
      for (int mt = 0; mt < 4; ++mt) {
        const int row = wm * 64 + mt * 16 + lrow;
        af[mt] = *reinterpret_cast<const f16x8*>(&As[row * 128 + (kbyte ^ ((row & 7) << 4))]);
      }
#pragma unroll
      for (int nt = 0; nt < 2; ++nt) {
        const int row = wn * 32 + nt * 16 + lrow;
        bf[nt] = *reinterpret_cast<const f16x8*>(&Bs[row * 128 + (kbyte ^ ((row & 7) << 4))]);
      }
#pragma unroll
      for (int mt = 0; mt < 4; ++mt)
#pragma unroll
        for (int nt = 0; nt < 2; ++nt)
          acc[mt][nt] = __builtin_amdgcn_mfma_f32_16x16x32_f16(af[mt], bf[nt], acc[mt][nt], 0, 0, 0);
    }
    __syncthreads();
  }

#pragma unroll
  for (int nt = 0; nt < 2; ++nt) {
    const int n = n0 + wn * 32 + nt * 16 + lrow;
    float bias = (MODE == 0) ? (b0[n] + b1[n]) : b0[n];
#pragma unroll
    for (int mt = 0; mt < 4; ++mt) {
#pragma unroll
      for (int r = 0; r < 4; ++r) {
        const int m = m0 + wm * 64 + mt * 16 + lq * 4 + r;
        float val = acc[mt][nt][r] + bias;
        if (MODE == 1) val = fmaxf(val, 0.f);
        if (MODE == 2) val = fast_tanh(val);
        if constexpr (sizeof(OT) == 2)
          C[(size_t)m * N + n] = __float2half_rn(val);
        else
          C[(size_t)m * N + n] = val;
      }
    }
  }
}

// ---------------------------------------------------------------------------
// Fused fw+bw input-projection GEMM, f16 output. blockIdx.z = direction.
// ---------------------------------------------------------------------------
template<typename AT>
__global__ __launch_bounds__(256) void gemm_proj_h(
    const AT* __restrict__ A,
    const float* __restrict__ W0, const float* __restrict__ W1,
    const float* __restrict__ bi0, const float* __restrict__ bh0,
    const float* __restrict__ bi1, const float* __restrict__ bh1,
    __half* __restrict__ C0, __half* __restrict__ C1, int M, int N, int K) {
  const float* __restrict__ W  = blockIdx.z ? W1 : W0;
  const float* __restrict__ b0 = blockIdx.z ? bi1 : bi0;
  const float* __restrict__ b1 = blockIdx.z ? bh1 : bh0;
  __half* __restrict__ C = blockIdx.z ? C1 : C0;

  __shared__ __align__(16) unsigned char As[128 * 128];
  __shared__ __align__(16) unsigned char Bs[64 * 128];
  const int tid = threadIdx.x;
  const int wave = tid >> 6, l = tid & 63;
  const int wm = wave >> 1, wn = wave & 1;
  const int m0 = blockIdx.x * 128, n0 = blockIdx.y * 64;
  const int lrow = l & 15, lq = l >> 4;

  f32x4 acc[4][2] = {};
  const int arow = tid >> 1, akc = (tid & 1) * 32;
  const int brow = tid >> 2, bkc = (tid & 3) * 16;

  for (int k0 = 0; k0 < K; k0 += 64) {
    stage_row32<AT>(A + (size_t)(m0 + arow) * K + k0 + akc, As, arow, akc);
    {
      const float* src = W + (size_t)(n0 + brow) * K + k0 + bkc;
#pragma unroll
      for (int u = 0; u < 2; ++u) {
        float4 v0 = *reinterpret_cast<const float4*>(src + u * 8);
        float4 v1 = *reinterpret_cast<const float4*>(src + u * 8 + 4);
        f16x8 h;
        h[0] = (_Float16)v0.x; h[1] = (_Float16)v0.y;
        h[2] = (_Float16)v0.z; h[3] = (_Float16)v0.w;
        h[4] = (_Float16)v1.x; h[5] = (_Float16)v1.y;
        h[6] = (_Float16)v1.z; h[7] = (_Float16)v1.w;
        const int kbyte = (bkc + u * 8) * 2;
        *reinterpret_cast<f16x8*>(&Bs[brow * 128 + (kbyte ^ ((brow & 7) << 4))]) = h;
      }
    }
    __syncthreads();
#pragma unroll
    for (int kk = 0; kk < 64; kk += 32) {
      const int kbyte = (kk + lq * 8) * 2;
      f16x8 af[4], bf[2];
#pragma unroll
      for (int mt = 0; mt < 4; ++mt) {
        const int row = wm * 64 + mt * 16 + lrow;
        af[mt] = *reinterpret_cast<const f16x8*>(&As[row * 128 + (kbyte ^ ((row & 7) << 4))]);
      }
#pragma unroll
      for (int nt = 0; nt < 2; ++nt) {
        const int row = wn * 32 + nt * 16 + lrow;
        bf[nt] = *reinterpret_cast<const f16x8*>(&Bs[row * 128 + (kbyte ^ ((row & 7) << 4))]);
      }
#pragma unroll
      for (int mt = 0; mt < 4; ++mt)
#pragma unroll
        for (int nt = 0; nt < 2; ++nt)
          acc[mt][nt] = __builtin_amdgcn_mfma_f32_16x16x32_f16(af[mt], bf[nt], acc[mt][nt], 0, 0, 0);
    }
    __syncthreads();
  }

#pragma unroll
  for (int nt = 0; nt < 2; ++nt) {
    const int n = n0 + wn * 32 + nt * 16 + lrow;
    const float bias = b0[n] + b1[n];
#pragma unroll
    for (int mt = 0; mt < 4; ++mt) {
#pragma unroll
      for (int r = 0; r < 4; ++r) {
        const int m = m0 + wm * 64 + mt * 16 + lq * 4 + r;
        C[(size_t)m * N + n] = __float2half_rn(acc[mt][nt][r] + bias);
      }
    }
  }
}

// ---------------------------------------------------------------------------
// LSTM recurrence, v9 = the 256-thread (1 wave/SIMD, 4-wave barrier) config,
// implemented WITHOUT array/reference constructs that triggered v8's
// LDS-alloca spill (16.9KB LDS, 5.7M bank conflicts):
//  - h quarter read into named uint4 q0..q3; components used directly.
//  - activation bodies fully written out (no float& ternary references).
//  - hbuf chunks padded to 24 dwords (96B): 16B-aligned ds_read_b128 AND
//    bank-disjoint across kq ({0-3},{24-27},{16-19},{8-11}).
// Lane (j2 = tid>>2, kq = tid&3): 8 gate-rows (2 units x 4 gates) over
// k-quarter = 128 dot2/lane. Quad DPP butterfly; lane kq activates gate kq
// for both units (tanh = 2*sigmoid(2x)-1); quad broadcasts redistribute.
// Raw s_barrier with lgkmcnt(0)-only wait; f16 xg prefetch depth 2.
// ---------------------------------------------------------------------------
__global__ __launch_bounds__(256, 1) void lstm_seq9(
    const __half* __restrict__ xg_f, const __half* __restrict__ xg_b,
    const float* __restrict__ Whh_f, const float* __restrict__ Whh_b,
    __half* __restrict__ out) {
  const int b = blockIdx.x;
  const int dir = blockIdx.y;
  const int tid = threadIdx.x;
  const int j2 = tid >> 2;  // unit pair 0..63
  const int kq = tid & 3;   // k quarter
  const __half* __restrict__ xg = dir ? xg_b : xg_f;
  const float* __restrict__ Whh = dir ? Whh_b : Whh_f;

  // [buf][chunk*24 + i]: chunk q holds h-pairs j2 in [16q,16q+16) at i=j2&15
  __shared__ unsigned int hbuf[2][96];

  // Weights: w[g][u][kk] = f16x2 of row (g*128 + 2*j2 + u), k = kq*32 + 2*kk
  unsigned int w[4][2][16];
#pragma unroll
  for (int g = 0; g < 4; ++g)
#pragma unroll
    for (int u = 0; u < 2; ++u) {
      const float4* wr = reinterpret_cast<const float4*>(
          Whh + (size_t)(g * 128 + 2 * j2 + u) * 128 + kq * 32);
#pragma unroll
      for (int q = 0; q < 8; ++q) {
        float4 v = wr[q];
        __half2 p0 = __floats2half2_rn(v.x, v.y);
        __half2 p1 = __floats2half2_rn(v.z, v.w);
        w[g][u][2 * q]     = __builtin_bit_cast(unsigned int, p0);
        w[g][u][2 * q + 1] = __builtin_bit_cast(unsigned int, p1);
      }
    }

  if (tid < 192) reinterpret_cast<unsigned int*>(hbuf)[tid] = 0u;
  float c0 = 0.f, c1 = 0.f;
  __syncthreads();

  const int tt0 = dir ? 511 : 0;
  const int stp = dir ? -1 : 1;
  const size_t base = (size_t)b * 512 * 512;
  const int xoff = kq * 128 + 2 * j2;  // f16 index: gate kq, units 2*j2,2*j2+1
  const bool hwriter = (kq == (j2 >> 4));
  const int wdst = (j2 >> 4) * 24 + (j2 & 15);

  unsigned int xva = *reinterpret_cast<const unsigned int*>(xg + base + (size_t)tt0 * 512 + xoff);
  unsigned int xvb = *reinterpret_cast<const unsigned int*>(xg + base + (size_t)(tt0 + stp) * 512 + xoff);

  auto step = [&](int t, unsigned int* rbuf, unsigned int* wbuf, unsigned int& xcur)
      __attribute__((always_inline)) {
    const int tt = tt0 + stp * t;

    // my h quarter: 4 x ds_read_b128 at 16B-aligned, bank-disjoint addrs
    const uint4* hc = reinterpret_cast<const uint4*>(&rbuf[kq * 24]);
    const uint4 q0 = hc[0], q1 = hc[1], q2 = hc[2], q3 = hc[3];

    float a00 = 0.f, a01 = 0.f, a10 = 0.f, a11 = 0.f;
    float a20 = 0.f, a21 = 0.f, a30 = 0.f, a31 = 0.f;
#define ACCUM(kk, hval)                          \
    a00 = fdot2u(w[0][0][kk], (hval), a00);      \
    a01 = fdot2u(w[0][1][kk], (hval), a01);      \
    a10 = fdot2u(w[1][0][kk], (hval), a10);      \
    a11 = fdot2u(w[1][1][kk], (hval), a11);      \
    a20 = fdot2u(w[2][0][kk], (hval), a20);      \
    a21 = fdot2u(w[2][1][kk], (hval), a21);      \
    a30 = fdot2u(w[3][0][kk], (hval), a30);      \
    a31 = fdot2u(w[3][1][kk], (hval), a31);
    ACCUM(0,  q0.x) ACCUM(1,  q0.y) ACCUM(2,  q0.z) ACCUM(3,  q0.w)
    ACCUM(4,  q1.x) ACCUM(5,  q1.y) ACCUM(6,  q1.z) ACCUM(7,  q1.w)
    ACCUM(8,  q2.x) ACCUM(9,  q2.y) ACCUM(10, q2.z) ACCUM(11, q2.w)
    ACCUM(12, q3.x) ACCUM(13, q3.y) ACCUM(14, q3.z) ACCUM(15, q3.w)
#undef ACCUM

    // quad butterfly: all 4 lanes get all 8 full sums
    a00 = dpp_add<0x4E>(dpp_add<0xB1>(a00));
    a01 = dpp_add<0x4E>(dpp_add<0xB1>(a01));
    a10 = dpp_add<0x4E>(dpp_add<0xB1>(a10));
    a11 = dpp_add<0x4E>(dpp_add<0xB1>(a11));
    a20 = dpp_add<0x4E>(dpp_add<0xB1>(a20));
    a21 = dpp_add<0x4E>(dpp_add<0xB1>(a21));
    a30 = dpp_add<0x4E>(dpp_add<0xB1>(a30));
    a31 = dpp_add<0x4E>(dpp_add<0xB1>(a31));

    const __half2 xh = __builtin_bit_cast(__half2, xcur);
    // prefetch xg for t+2 (stays in flight across raw barriers)
    {
      const int t2 = t + 2;
      const int tt2 = (t2 < 512) ? (tt0 + stp * t2) : tt0;
      xcur = *reinterpret_cast<const unsigned int*>(xg + base + (size_t)tt2 * 512 + xoff);
    }

    // ---- u = 0: lane kq activates gate kq of unit 2*j2 ----
    float s0 = a00;
    s0 = (kq == 1) ? a10 : s0;
    s0 = (kq == 2) ? a20 : s0;
    s0 = (kq == 3) ? a30 : s0;
    s0 += __low2float(xh);
    {
      const float xs = (kq == 2) ? 2.f * s0 : s0;
      const float y = fast_sigmoid(xs);
      const float act = (kq == 2) ? 2.f * y - 1.f : y;
      const float gi = dpp_mov<0x00>(act);
      const float gf = dpp_mov<0x55>(act);
      const float gg = dpp_mov<0xAA>(act);
      const float go = dpp_mov<0xFF>(act);
      c0 = gf * c0 + gi * gg;
      s0 = go * (2.f * fast_sigmoid(2.f * c0) - 1.f);  // h0
    }

    // ---- u = 1: lane kq activates gate kq of unit 2*j2+1 ----
    float s1 = a01;
    s1 = (kq == 1) ? a11 : s1;
    s1 = (kq == 2) ? a21 : s1;
    s1 = (kq == 3) ? a31 : s1;
    s1 += __high2float(xh);
    {
      const float xs = (kq == 2) ? 2.f * s1 : s1;
      const float y = fast_sigmoid(xs);
      const float act = (kq == 2) ? 2.f * y - 1.f : y;
      const float gi = dpp_mov<0x00>(act);
      const float gf = dpp_mov<0x55>(act);
      const float gg = dpp_mov<0xAA>(act);
      const float go = dpp_mov<0xFF>(act);
      c1 = gf * c1 + gi * gg;
      s1 = go * (2.f * fast_sigmoid(2.f * c1) - 1.f);  // h1
    }

    const __half2 hp = __floats2half2_rn(s0, s1);
    if (hwriter) {  // h pair -> next step's buffer (16 lanes/wave, disjoint banks)
      wbuf[wdst] = __builtin_bit_cast(unsigned int, hp);
    }
    if (kq == 1) {  // h pair -> global out (f16)
      *reinterpret_cast<__half2*>(
          out + ((size_t)b * 512 + tt) * 256 + dir * 128 + 2 * j2) = hp;
    }

    asm volatile("s_waitcnt lgkmcnt(0)" ::: "memory");
    __builtin_amdgcn_s_barrier();
    asm volatile("" ::: "memory");
  };

  for (int it = 0; it < 256; ++it) {
    step(2 * it,     hbuf[0], hbuf[1], xva);
    step(2 * it + 1, hbuf[1], hbuf[0], xvb);
  }
}

// ---------------------------------------------------------------------------
// Launcher
// ---------------------------------------------------------------------------
extern "C" void kernel_launch(void* const* d_in, const int* in_sizes, int n_in,
                              void* d_out, int out_size, void* d_ws, size_t ws_size,
                              hipStream_t stream) {
  (void)in_sizes; (void)n_in; (void)out_size; (void)ws_size;

  const float* x     = (const float*)d_in[0];
  const float* Wih00 = (const float*)d_in[1];
  const float* Whh00 = (const float*)d_in[2];
  const float* bih00 = (const float*)d_in[3];
  const float* bhh00 = (const float*)d_in[4];
  const float* Wih01 = (const float*)d_in[5];
  const float* Whh01 = (const float*)d_in[6];
  const float* bih01 = (const float*)d_in[7];
  const float* bhh01 = (const float*)d_in[8];
  const float* Wih10 = (const float*)d_in[9];
  const float* Whh10 = (const float*)d_in[10];
  const float* bih10 = (const float*)d_in[11];
  const float* bhh10 = (const float*)d_in[12];
  const float* Wih11 = (const float*)d_in[13];
  const float* Whh11 = (const float*)d_in[14];
  const float* bih11 = (const float*)d_in[15];
  const float* bhh11 = (const float*)d_in[16];
  const float* W1 = (const float*)d_in[17];
  const float* b1 = (const float*)d_in[18];
  const float* W2 = (const float*)d_in[19];
  const float* b2 = (const float*)d_in[20];
  float* out = (float*)d_out;

  char* ws = (char*)d_ws;
  __half* xgh_f = (__half*)ws;                          // 32 MB [B,T,512] f16
  __half* xgh_b = (__half*)(ws + ((size_t)32 << 20));   // 32 MB
  __half* bufh  = (__half*)(ws + ((size_t)64 << 20));   // 16 MB [B,T,256] f16
  __half* tmph  = (__half*)(ws + ((size_t)80 << 20));   // 16 MB head intermediate

  const int M = 64 * 512;  // 32768 rows

  // ---- layer 0 ----
  gemm_proj_h<float><<<dim3(M / 128, 8, 2), 256, 0, stream>>>(
      x, Wih00, Wih01, bih00, bhh00, bih01, bhh01, xgh_f, xgh_b, M, 512, 64);
  lstm_seq9<<<dim3(64, 2), 256, 0, stream>>>(xgh_f, xgh_b, Whh00, Whh01, bufh);

  // ---- layer 1 ----
  gemm_proj_h<__half><<<dim3(M / 128, 8, 2), 256, 0, stream>>>(
      bufh, Wih10, Wih11, bih10, bhh10, bih11, bhh11, xgh_f, xgh_b, M, 512, 256);
  lstm_seq9<<<dim3(64, 2), 256, 0, stream>>>(xgh_f, xgh_b, Whh10, Whh11, bufh);

  // ---- head ----
  gemm_mfma2<__half, __half, 1><<<dim3(M / 128, 4), 256, 0, stream>>>(
      bufh, W1, b1, nullptr, tmph, M, 256, 256);
  gemm_mfma2<__half, float, 2><<<dim3(M / 128, 1), 256, 0, stream>>>(
      tmph, W2, b2, nullptr, out, M, 64, 256);
}